// Round 6
// baseline (277.640 us; speedup 1.0000x reference)
//
#include <hip/hip_runtime.h>
#include <hip/hip_bf16.h>
#include <stdint.h>

#define NTOT  8192
#define DIM   512
#define NI    8
#define NWAYS 1024
#define TILE  128
#define BK    128
#define NSYM  2080   /* 64*65/2 upper-triangle tile pairs */
#define NBLK  2592   /* NSYM + 512 proto blocks = 8 * 324 */
#define MARGINV 0.3f

typedef float f32x4 __attribute__((ext_vector_type(4)));

// order-preserving float<->uint map (monotonic for all finite floats +/- inf)
__device__ __forceinline__ unsigned f2o(float f) {
  unsigned u = __float_as_uint(f);
  return (u & 0x80000000u) ? ~u : (u | 0x80000000u);
}
__device__ __forceinline__ float o2f(unsigned u) {
  u = (u & 0x80000000u) ? (u & 0x7fffffffu) : ~u;
  return __uint_as_float(u);
}

__device__ __forceinline__ float wave_sum64(float v) {
#pragma unroll
  for (int s = 32; s; s >>= 1) v += __shfl_xor(v, s, 64);
  return v;
}

__device__ __forceinline__ void async_ld16(const void* g, void* l) {
  __builtin_amdgcn_global_load_lds(
      (__attribute__((address_space(1))) void*)(uintptr_t)g,
      (__attribute__((address_space(3))) void*)l, 16, 0, 0);
}

// ---- prep: sq-norms + fp8(e4m3) cast + accumulator init; protos in tail ----
__global__ __launch_bounds__(256) void prep(
    const float* __restrict__ A, float* __restrict__ sq,
    float* __restrict__ psq, unsigned char* __restrict__ A8,
    unsigned char* __restrict__ P8,
    unsigned* __restrict__ an_u32, unsigned* __restrict__ ap_u32,
    unsigned long long* __restrict__ pr_key, unsigned* __restrict__ cnt) {
  const int w = threadIdx.x >> 6;
  const int l = threadIdx.x & 63;
  const int b = blockIdx.x;
  if (b == 0 && threadIdx.x == 0) *cnt = 0u;  // completion counter re-poison
  if (b < NTOT / 4) {
    const int row = b * 4 + w;
    const float4* rp = (const float4*)(A + (size_t)row * DIM);
    unsigned* op = (unsigned*)(A8 + (size_t)row * DIM);
    float s = 0.f;
#pragma unroll
    for (int m = 0; m < 2; ++m) {
      const float4 v = rp[l + 64 * m];
      s = fmaf(v.x, v.x, fmaf(v.y, v.y, fmaf(v.z, v.z, fmaf(v.w, v.w, s))));
      int wd = 0;
      wd = __builtin_amdgcn_cvt_pk_fp8_f32(v.x, v.y, wd, false);
      wd = __builtin_amdgcn_cvt_pk_fp8_f32(v.z, v.w, wd, true);
      op[l + 64 * m] = (unsigned)wd;
    }
    s = wave_sum64(s);
    if (l == 0) {
      sq[row] = s;
      an_u32[row] = ~0u;
      ap_u32[row] = 0u;
      pr_key[row] = ~0ull;
    }
  } else {
    const int c = (b - NTOT / 4) * 4 + w;  // proto id
    unsigned* op = (unsigned*)(P8 + (size_t)c * DIM);
    float s = 0.f;
#pragma unroll
    for (int m = 0; m < 2; ++m) {
      float4 p = {0.f, 0.f, 0.f, 0.f};
#pragma unroll
      for (int r = 0; r < NI; ++r) {
        const float4 v =
            ((const float4*)(A + (size_t)(c * NI + r) * DIM))[l + 64 * m];
        p.x += v.x; p.y += v.y; p.z += v.z; p.w += v.w;
      }
      p.x *= (1.f / NI); p.y *= (1.f / NI); p.z *= (1.f / NI); p.w *= (1.f / NI);
      s = fmaf(p.x, p.x, fmaf(p.y, p.y, fmaf(p.z, p.z, fmaf(p.w, p.w, s))));
      int wd = 0;
      wd = __builtin_amdgcn_cvt_pk_fp8_f32(p.x, p.y, wd, false);
      wd = __builtin_amdgcn_cvt_pk_fp8_f32(p.z, p.w, wd, true);
      op[l + 64 * m] = (unsigned)wd;
    }
    s = wave_sum64(s);
    if (l == 0) psq[c] = s;
  }
}

// ---- fused symmetric fp8 GEMM + min/max epilogues, BK=128 dbuf ----
// RESTORED to the round-0 structure (best measured: 68 us) after five
// alternative schedules (counted-vmcnt, BK=64, 3-ring, 256x128 tile,
// persistent+resident-A) all landed at 75-83 us. New: finalize merged in
// via last-block completion counter (saves one kernel dispatch).
// LDS layout: 128-B rows, 8x16-B units, unit u of row r stored at u^(r&7).
__global__ __launch_bounds__(256) void gemm_fused(
    const unsigned char* __restrict__ A, const unsigned char* __restrict__ P,
    const float* __restrict__ sq, const float* __restrict__ psq,
    unsigned* __restrict__ an_u32, unsigned* __restrict__ ap_u32,
    unsigned long long* __restrict__ pr_key, float* __restrict__ out,
    unsigned* __restrict__ cnt) {
  __shared__ __align__(16) unsigned char As[2][TILE * BK];  // 2 x 16 KB
  __shared__ __align__(16) unsigned char Bs[2][TILE * BK];  // 2 x 16 KB
  __shared__ unsigned rmin[TILE];
  __shared__ unsigned cmin[TILE];
  __shared__ unsigned amax[TILE];
  __shared__ unsigned long long rowkey[TILE][2];  // proto path only
  __shared__ float fin_red[4][4];
  __shared__ unsigned lastflag;

  const int braw = blockIdx.x;
  const int b = (braw & 7) * (NBLK / 8) + (braw >> 3);  // XCD-contiguous
  const bool isProto = b >= NSYM;
  int bi, bj;
  const unsigned char* Bmat;
  const float* sqB;
  if (!isProto) {
    // supertile decode: pairs (Si<=Sj) of 8x8-tile supertiles
    int rem = b, Si = 0, Sj = 0;
    for (;;) {
      const int cnt2 = (Si == Sj) ? 36 : 64;
      if (rem < cnt2) break;
      rem -= cnt2;
      ++Si;
      if (Si > Sj) { Si = 0; ++Sj; }
    }
    int bi_l, bj_l;
    if (Si == Sj) {
      bj_l = 0;
      while ((bj_l + 1) * (bj_l + 2) / 2 <= rem) ++bj_l;
      bi_l = rem - bj_l * (bj_l + 1) / 2;
    } else {
      bi_l = rem & 7;
      bj_l = rem >> 3;
    }
    bi = Si * 8 + bi_l;
    bj = Sj * 8 + bj_l;
    Bmat = A;
    sqB = sq;
  } else {
    const int p = b - NSYM;
    bj = p & 7;
    bi = p >> 3;
    Bmat = P;
    sqB = psq;
  }
  const int rowBase = bi * TILE;
  const int colBase = bj * TILE;
  const bool isDiag = !isProto && (bi == bj);
  const bool colSide = !isProto && (bi != bj);

  const int t = threadIdx.x;
  const int lane = t & 63;
  const int wv = t >> 6;
  const int wr = wv >> 1;
  const int wc = wv & 1;
  const int quad = lane >> 4;
  const int lc = lane & 15;

  if (t < TILE) { rmin[t] = ~0u; cmin[t] = ~0u; amax[t] = 0u; }

  // fragment-read unit offsets per 32-k chunk c: unit = (2c + quad/2) ^ (lc&7)
  int koff[4];
#pragma unroll
  for (int c = 0; c < 4; ++c)
    koff[c] = (((c * 2 + (quad >> 1)) ^ (lc & 7)) * 16) + (quad & 1) * 8;

  int rowA[4], rowB[4];
#pragma unroll
  for (int x = 0; x < 4; ++x) {
    rowA[x] = (wr * 64 + x * 16 + lc) * BK;
    rowB[x] = (wc * 64 + x * 16 + lc) * BK;
  }

  // staging: lane covers (row = rr*8 + lane/8, phys unit = lane&7);
  // logical source unit = (lane&7) ^ (row&7). Wave wv does rounds wv*4..wv*4+3.
  const int l8 = lane >> 3;
  const int ul = ((lane & 7) ^ (l8 & 7)) * 16;
  const unsigned char* gA = A + (size_t)(rowBase + l8) * DIM + ul;
  const unsigned char* gB = Bmat + (size_t)(colBase + l8) * DIM + ul;
  const int ldsL = lane * 16;

  f32x4 acc[4][4] = {};

  // prologue: stage K-tile 0 into buffer 0
#pragma unroll
  for (int j = 0; j < 4; ++j) {
    const int rr = wv * 4 + j;
    async_ld16(gA + (size_t)rr * 8 * DIM, &As[0][rr * 1024 + ldsL]);
    async_ld16(gB + (size_t)rr * 8 * DIM, &Bs[0][rr * 1024 + ldsL]);
  }
  __syncthreads();

#pragma unroll
  for (int it = 0; it < 4; ++it) {
    const int cur = it & 1;
    const int nxt = cur ^ 1;
    const int kt = it * BK;
    if (it < 3) {  // issue-ahead next K-tile
#pragma unroll
      for (int j = 0; j < 4; ++j) {
        const int rr = wv * 4 + j;
        async_ld16(gA + (size_t)rr * 8 * DIM + kt + BK, &As[nxt][rr * 1024 + ldsL]);
        async_ld16(gB + (size_t)rr * 8 * DIM + kt + BK, &Bs[nxt][rr * 1024 + ldsL]);
      }
    }
    const unsigned char* Ac = &As[cur][0];
    const unsigned char* Bc = &Bs[cur][0];
#pragma unroll
    for (int c = 0; c < 4; ++c) {
      long af[4], bfr[4];
#pragma unroll
      for (int x = 0; x < 4; ++x) {
        af[x]  = *(const long*)(Ac + rowA[x] + koff[c]);
        bfr[x] = *(const long*)(Bc + rowB[x] + koff[c]);
      }
#pragma unroll
      for (int x = 0; x < 4; ++x)
#pragma unroll
        for (int y = 0; y < 4; ++y)
          acc[x][y] = __builtin_amdgcn_mfma_f32_16x16x32_fp8_fp8(
              af[x], bfr[y], acc[x][y], 0, 0, 0);
    }
    __syncthreads();  // publishes buf[nxt]; all reads of buf[cur] done
  }

  // ---- epilogue. C/D layout: col=lane&15, row=quad*4+reg ----
  float sb[4];
#pragma unroll
  for (int y = 0; y < 4; ++y) sb[y] = sqB[colBase + wc * 64 + y * 16 + lc];

  const float INF = __int_as_float(0x7f800000);

  if (!isProto) {
    // row-side: per-lane min over y, then one LDS u32-min atomic per (x,r)
#pragma unroll
    for (int x = 0; x < 4; ++x) {
#pragma unroll
      for (int r = 0; r < 4; ++r) {
        const int row = rowBase + wr * 64 + x * 16 + quad * 4 + r;
        float mv = INF, mx = -INF;
#pragma unroll
        for (int y = 0; y < 4; ++y) {
          const float v = fmaf(-2.f, acc[x][y][r], sb[y]);
          if (isDiag) {
            const int col = colBase + wc * 64 + y * 16 + lc;
            const bool same = (row >> 3) == (col >> 3);
            mv = fminf(mv, same ? INF : v);
            mx = fmaxf(mx, same ? v : -INF);
          } else {
            mv = fminf(mv, v);
          }
        }
        atomicMin(&rmin[row - rowBase], f2o(mv));
        if (isDiag) atomicMax(&amax[row - rowBase], f2o(mx));
      }
    }
    // col-side (off-diag): per-lane min over (x,r) per y
    if (colSide) {
      float sa[4][4];
#pragma unroll
      for (int x = 0; x < 4; ++x)
#pragma unroll
        for (int r = 0; r < 4; ++r)
          sa[x][r] = sq[rowBase + wr * 64 + x * 16 + quad * 4 + r];
#pragma unroll
      for (int y = 0; y < 4; ++y) {
        float cv = INF;
#pragma unroll
        for (int x = 0; x < 4; ++x)
#pragma unroll
          for (int r = 0; r < 4; ++r)
            cv = fminf(cv, fmaf(-2.f, acc[x][y][r], sa[x][r]));
        atomicMin(&cmin[wc * 64 + y * 16 + lc], f2o(cv));
      }
    }
  } else {
    // proto path: need argmin index -> u64 keys + 16-lane butterfly
#pragma unroll
    for (int x = 0; x < 4; ++x) {
      unsigned long long kmin[4] = {~0ull, ~0ull, ~0ull, ~0ull};
#pragma unroll
      for (int y = 0; y < 4; ++y) {
        const int col = colBase + wc * 64 + y * 16 + lc;
#pragma unroll
        for (int r = 0; r < 4; ++r) {
          const float v = fmaf(-2.f, acc[x][y][r], sb[y]);
          const unsigned long long kn =
              ((unsigned long long)f2o(v) << 32) | (unsigned)col;
          if (kn < kmin[r]) kmin[r] = kn;
        }
      }
#pragma unroll
      for (int r = 0; r < 4; ++r) {
#pragma unroll
        for (int s = 1; s < 16; s <<= 1) {
          const unsigned long long o = __shfl_xor(kmin[r], s, 64);
          if (o < kmin[r]) kmin[r] = o;
        }
      }
      if (lc == 0) {
#pragma unroll
        for (int r = 0; r < 4; ++r)
          rowkey[wr * 64 + x * 16 + quad * 4 + r][wc] = kmin[r];
      }
    }
  }

  __syncthreads();
  if (isProto) {
    if (t < TILE) {
      unsigned long long a = rowkey[t][0];
      const unsigned long long c = rowkey[t][1];
      if (c < a) a = c;
      atomicMin(pr_key + rowBase + t, a);
    }
  } else {
    if (t < TILE) {
      atomicMin(an_u32 + rowBase + t, rmin[t]);
    } else if (t < 2 * TILE) {
      const int i = t - TILE;
      if (colSide) atomicMin(an_u32 + colBase + i, cmin[i]);
      else if (isDiag) atomicMax(ap_u32 + rowBase + i, amax[i]);
    }
  }

  // ---- last-block finalize (replaces the separate finalize_kernel) ----
  // Every thread fences its own device-scope atomics, barrier, then one
  // counter bump per block. The block observing NBLK-1 knows all other
  // blocks' atomics completed (each drained vmcnt before its barrier).
  __threadfence();
  __syncthreads();
  if (t == 0) lastflag = atomicAdd(cnt, 1u);
  __syncthreads();
  if (lastflag == NBLK - 1) {
    float loss = 0.f, sp = 0.f, sn = 0.f, accv = 0.f;
#pragma unroll 8
    for (int i = t; i < NTOT; i += 256) {
      const float s = sq[i];
      const unsigned apu = __hip_atomic_load(&ap_u32[i], __ATOMIC_RELAXED,
                                             __HIP_MEMORY_SCOPE_AGENT);
      const unsigned anu = __hip_atomic_load(&an_u32[i], __ATOMIC_RELAXED,
                                             __HIP_MEMORY_SCOPE_AGENT);
      const unsigned long long pk = __hip_atomic_load(
          &pr_key[i], __ATOMIC_RELAXED, __HIP_MEMORY_SCOPE_AGENT);
      const float apv = sqrtf(fmaxf(s + o2f(apu), 1e-12f));
      const float anv = sqrtf(fmaxf(s + o2f(anu), 1e-12f));
      loss += fmaxf(apv - anv + MARGINV, 0.f);
      sp += apv;
      sn += anv;
      accv += ((unsigned)(pk & 0xffffffffu) == (unsigned)(i >> 3)) ? 1.f : 0.f;
    }
    loss = wave_sum64(loss);
    sp = wave_sum64(sp);
    sn = wave_sum64(sn);
    accv = wave_sum64(accv);
    if (lane == 0) {
      fin_red[wv][0] = loss;
      fin_red[wv][1] = accv;
      fin_red[wv][2] = sp;
      fin_red[wv][3] = sn;
    }
    __syncthreads();
    if (t == 0) {
      float L = 0, Ac = 0, Pm = 0, Nn = 0;
#pragma unroll
      for (int i = 0; i < 4; ++i) {
        L += fin_red[i][0];
        Ac += fin_red[i][1];
        Pm += fin_red[i][2];
        Nn += fin_red[i][3];
      }
      out[0] = L / NTOT;   // W = 1.0
      out[1] = Ac / NTOT;
      out[2] = Pm / NTOT;
      out[3] = Nn / NTOT;
    }
  }
}

extern "C" void kernel_launch(void* const* d_in, const int* in_sizes, int n_in,
                              void* d_out, int out_size, void* d_ws, size_t ws_size,
                              hipStream_t stream) {
  const float* inputs = (const float*)d_in[0];
  float* out = (float*)d_out;
  char* w = (char*)d_ws;
  float* sq  = (float*)(w);                                       // 32 KB
  float* psq = (float*)(w + 32768);                               // 4 KB
  unsigned* an_u32 = (unsigned*)(w + 36864);                      // 32 KB
  unsigned* ap_u32 = (unsigned*)(w + 69632);                      // 32 KB
  unsigned long long* pr_key = (unsigned long long*)(w + 102400); // 64 KB
  unsigned char* A8 = (unsigned char*)(w + 167936);               // 4 MB
  unsigned char* P8 = (unsigned char*)(w + 167936 + (size_t)NTOT * DIM);
  unsigned* cnt = (unsigned*)(w + 167936 + (size_t)NTOT * DIM
                              + (size_t)NWAYS * DIM);             // +4 B

  prep<<<NTOT / 4 + NWAYS / 4, 256, 0, stream>>>(inputs, sq, psq, A8, P8,
                                                 an_u32, ap_u32, pr_key, cnt);
  gemm_fused<<<NBLK, 256, 0, stream>>>(A8, P8, sq, psq,
                                       an_u32, ap_u32, pr_key, out, cnt);
}

// Round 7
// 141.223 us; speedup vs baseline: 1.9660x; 1.9660x over previous
//
#include <hip/hip_runtime.h>
#include <hip/hip_bf16.h>
#include <stdint.h>

#define NTOT  8192
#define DIM   512
#define NI    8
#define NWAYS 1024
#define TILE  128
#define BK    128
#define NSYM  2080   /* 64*65/2 upper-triangle tile pairs */
#define NBLK  2592   /* NSYM + 512 proto blocks = 8 * 324 */
#define MARGINV 0.3f

typedef float f32x4 __attribute__((ext_vector_type(4)));

// order-preserving float<->uint map (monotonic for all finite floats +/- inf)
__device__ __forceinline__ unsigned f2o(float f) {
  unsigned u = __float_as_uint(f);
  return (u & 0x80000000u) ? ~u : (u | 0x80000000u);
}
__device__ __forceinline__ float o2f(unsigned u) {
  u = (u & 0x80000000u) ? (u & 0x7fffffffu) : ~u;
  return __uint_as_float(u);
}

__device__ __forceinline__ float wave_sum64(float v) {
#pragma unroll
  for (int s = 32; s; s >>= 1) v += __shfl_xor(v, s, 64);
  return v;
}

__device__ __forceinline__ void async_ld16(const void* g, void* l) {
  __builtin_amdgcn_global_load_lds(
      (__attribute__((address_space(1))) void*)(uintptr_t)g,
      (__attribute__((address_space(3))) void*)l, 16, 0, 0);
}

// ---- prep: sq-norms + fp8(e4m3) cast + accumulator init; protos in tail ----
__global__ __launch_bounds__(256) void prep(
    const float* __restrict__ A, float* __restrict__ sq,
    float* __restrict__ psq, unsigned char* __restrict__ A8,
    unsigned char* __restrict__ P8,
    unsigned* __restrict__ an_u32, unsigned* __restrict__ ap_u32,
    unsigned long long* __restrict__ pr_key, unsigned* __restrict__ cnt) {
  const int w = threadIdx.x >> 6;
  const int l = threadIdx.x & 63;
  const int b = blockIdx.x;
  if (b == 0 && threadIdx.x == 0) *cnt = 0u;  // completion counter re-poison
  if (b < NTOT / 4) {
    const int row = b * 4 + w;
    const float4* rp = (const float4*)(A + (size_t)row * DIM);
    unsigned* op = (unsigned*)(A8 + (size_t)row * DIM);
    float s = 0.f;
#pragma unroll
    for (int m = 0; m < 2; ++m) {
      const float4 v = rp[l + 64 * m];
      s = fmaf(v.x, v.x, fmaf(v.y, v.y, fmaf(v.z, v.z, fmaf(v.w, v.w, s))));
      int wd = 0;
      wd = __builtin_amdgcn_cvt_pk_fp8_f32(v.x, v.y, wd, false);
      wd = __builtin_amdgcn_cvt_pk_fp8_f32(v.z, v.w, wd, true);
      op[l + 64 * m] = (unsigned)wd;
    }
    s = wave_sum64(s);
    if (l == 0) {
      sq[row] = s;
      an_u32[row] = ~0u;
      ap_u32[row] = 0u;
      pr_key[row] = ~0ull;
    }
  } else {
    const int c = (b - NTOT / 4) * 4 + w;  // proto id
    unsigned* op = (unsigned*)(P8 + (size_t)c * DIM);
    float s = 0.f;
#pragma unroll
    for (int m = 0; m < 2; ++m) {
      float4 p = {0.f, 0.f, 0.f, 0.f};
#pragma unroll
      for (int r = 0; r < NI; ++r) {
        const float4 v =
            ((const float4*)(A + (size_t)(c * NI + r) * DIM))[l + 64 * m];
        p.x += v.x; p.y += v.y; p.z += v.z; p.w += v.w;
      }
      p.x *= (1.f / NI); p.y *= (1.f / NI); p.z *= (1.f / NI); p.w *= (1.f / NI);
      s = fmaf(p.x, p.x, fmaf(p.y, p.y, fmaf(p.z, p.z, fmaf(p.w, p.w, s))));
      int wd = 0;
      wd = __builtin_amdgcn_cvt_pk_fp8_f32(p.x, p.y, wd, false);
      wd = __builtin_amdgcn_cvt_pk_fp8_f32(p.z, p.w, wd, true);
      op[l + 64 * m] = (unsigned)wd;
    }
    s = wave_sum64(s);
    if (l == 0) psq[c] = s;
  }
}

// ---- fused symmetric fp8 GEMM + min/max epilogues, BK=128 dbuf ----
// Round-0 K-loop structure (best measured: 68 us across 6 schedule
// variants). Finalize merged via last-block completion counter (saves one
// dispatch, ~12 us — validated in R6). R6's 3x regression was the
// __threadfence() (agent-scope fence = L2 writeback/invalidate per block);
// replaced by a plain per-wave vmcnt(0) drain: all cross-block state is
// device-scope global atomics, already coherent once retired — only
// program-order completion before the counter bump is needed.
// LDS layout: 128-B rows, 8x16-B units, unit u of row r stored at u^(r&7).
__global__ __launch_bounds__(256) void gemm_fused(
    const unsigned char* __restrict__ A, const unsigned char* __restrict__ P,
    const float* __restrict__ sq, const float* __restrict__ psq,
    unsigned* __restrict__ an_u32, unsigned* __restrict__ ap_u32,
    unsigned long long* __restrict__ pr_key, float* __restrict__ out,
    unsigned* __restrict__ cnt) {
  __shared__ __align__(16) unsigned char As[2][TILE * BK];  // 2 x 16 KB
  __shared__ __align__(16) unsigned char Bs[2][TILE * BK];  // 2 x 16 KB
  __shared__ unsigned rmin[TILE];
  __shared__ unsigned cmin[TILE];
  __shared__ unsigned amax[TILE];
  __shared__ unsigned long long rowkey[TILE][2];  // proto path only
  __shared__ float fin_red[4][4];
  __shared__ unsigned lastflag;

  const int braw = blockIdx.x;
  const int b = (braw & 7) * (NBLK / 8) + (braw >> 3);  // XCD-contiguous
  const bool isProto = b >= NSYM;
  int bi, bj;
  const unsigned char* Bmat;
  const float* sqB;
  if (!isProto) {
    // supertile decode: pairs (Si<=Sj) of 8x8-tile supertiles
    int rem = b, Si = 0, Sj = 0;
    for (;;) {
      const int cnt2 = (Si == Sj) ? 36 : 64;
      if (rem < cnt2) break;
      rem -= cnt2;
      ++Si;
      if (Si > Sj) { Si = 0; ++Sj; }
    }
    int bi_l, bj_l;
    if (Si == Sj) {
      bj_l = 0;
      while ((bj_l + 1) * (bj_l + 2) / 2 <= rem) ++bj_l;
      bi_l = rem - bj_l * (bj_l + 1) / 2;
    } else {
      bi_l = rem & 7;
      bj_l = rem >> 3;
    }
    bi = Si * 8 + bi_l;
    bj = Sj * 8 + bj_l;
    Bmat = A;
    sqB = sq;
  } else {
    const int p = b - NSYM;
    bj = p & 7;
    bi = p >> 3;
    Bmat = P;
    sqB = psq;
  }
  const int rowBase = bi * TILE;
  const int colBase = bj * TILE;
  const bool isDiag = !isProto && (bi == bj);
  const bool colSide = !isProto && (bi != bj);

  const int t = threadIdx.x;
  const int lane = t & 63;
  const int wv = t >> 6;
  const int wr = wv >> 1;
  const int wc = wv & 1;
  const int quad = lane >> 4;
  const int lc = lane & 15;

  if (t < TILE) { rmin[t] = ~0u; cmin[t] = ~0u; amax[t] = 0u; }

  // fragment-read unit offsets per 32-k chunk c: unit = (2c + quad/2) ^ (lc&7)
  int koff[4];
#pragma unroll
  for (int c = 0; c < 4; ++c)
    koff[c] = (((c * 2 + (quad >> 1)) ^ (lc & 7)) * 16) + (quad & 1) * 8;

  int rowA[4], rowB[4];
#pragma unroll
  for (int x = 0; x < 4; ++x) {
    rowA[x] = (wr * 64 + x * 16 + lc) * BK;
    rowB[x] = (wc * 64 + x * 16 + lc) * BK;
  }

  // staging: lane covers (row = rr*8 + lane/8, phys unit = lane&7);
  // logical source unit = (lane&7) ^ (row&7). Wave wv does rounds wv*4..wv*4+3.
  const int l8 = lane >> 3;
  const int ul = ((lane & 7) ^ (l8 & 7)) * 16;
  const unsigned char* gA = A + (size_t)(rowBase + l8) * DIM + ul;
  const unsigned char* gB = Bmat + (size_t)(colBase + l8) * DIM + ul;
  const int ldsL = lane * 16;

  f32x4 acc[4][4] = {};

  // prologue: stage K-tile 0 into buffer 0
#pragma unroll
  for (int j = 0; j < 4; ++j) {
    const int rr = wv * 4 + j;
    async_ld16(gA + (size_t)rr * 8 * DIM, &As[0][rr * 1024 + ldsL]);
    async_ld16(gB + (size_t)rr * 8 * DIM, &Bs[0][rr * 1024 + ldsL]);
  }
  __syncthreads();

#pragma unroll
  for (int it = 0; it < 4; ++it) {
    const int cur = it & 1;
    const int nxt = cur ^ 1;
    const int kt = it * BK;
    if (it < 3) {  // issue-ahead next K-tile
#pragma unroll
      for (int j = 0; j < 4; ++j) {
        const int rr = wv * 4 + j;
        async_ld16(gA + (size_t)rr * 8 * DIM + kt + BK, &As[nxt][rr * 1024 + ldsL]);
        async_ld16(gB + (size_t)rr * 8 * DIM + kt + BK, &Bs[nxt][rr * 1024 + ldsL]);
      }
    }
    const unsigned char* Ac = &As[cur][0];
    const unsigned char* Bc = &Bs[cur][0];
#pragma unroll
    for (int c = 0; c < 4; ++c) {
      long af[4], bfr[4];
#pragma unroll
      for (int x = 0; x < 4; ++x) {
        af[x]  = *(const long*)(Ac + rowA[x] + koff[c]);
        bfr[x] = *(const long*)(Bc + rowB[x] + koff[c]);
      }
#pragma unroll
      for (int x = 0; x < 4; ++x)
#pragma unroll
        for (int y = 0; y < 4; ++y)
          acc[x][y] = __builtin_amdgcn_mfma_f32_16x16x32_fp8_fp8(
              af[x], bfr[y], acc[x][y], 0, 0, 0);
    }
    __syncthreads();  // publishes buf[nxt]; all reads of buf[cur] done
  }

  // ---- epilogue. C/D layout: col=lane&15, row=quad*4+reg ----
  float sb[4];
#pragma unroll
  for (int y = 0; y < 4; ++y) sb[y] = sqB[colBase + wc * 64 + y * 16 + lc];

  const float INF = __int_as_float(0x7f800000);

  if (!isProto) {
    // row-side: per-lane min over y, then one LDS u32-min atomic per (x,r)
#pragma unroll
    for (int x = 0; x < 4; ++x) {
#pragma unroll
      for (int r = 0; r < 4; ++r) {
        const int row = rowBase + wr * 64 + x * 16 + quad * 4 + r;
        float mv = INF, mx = -INF;
#pragma unroll
        for (int y = 0; y < 4; ++y) {
          const float v = fmaf(-2.f, acc[x][y][r], sb[y]);
          if (isDiag) {
            const int col = colBase + wc * 64 + y * 16 + lc;
            const bool same = (row >> 3) == (col >> 3);
            mv = fminf(mv, same ? INF : v);
            mx = fmaxf(mx, same ? v : -INF);
          } else {
            mv = fminf(mv, v);
          }
        }
        atomicMin(&rmin[row - rowBase], f2o(mv));
        if (isDiag) atomicMax(&amax[row - rowBase], f2o(mx));
      }
    }
    // col-side (off-diag): per-lane min over (x,r) per y
    if (colSide) {
      float sa[4][4];
#pragma unroll
      for (int x = 0; x < 4; ++x)
#pragma unroll
        for (int r = 0; r < 4; ++r)
          sa[x][r] = sq[rowBase + wr * 64 + x * 16 + quad * 4 + r];
#pragma unroll
      for (int y = 0; y < 4; ++y) {
        float cv = INF;
#pragma unroll
        for (int x = 0; x < 4; ++x)
#pragma unroll
          for (int r = 0; r < 4; ++r)
            cv = fminf(cv, fmaf(-2.f, acc[x][y][r], sa[x][r]));
        atomicMin(&cmin[wc * 64 + y * 16 + lc], f2o(cv));
      }
    }
  } else {
    // proto path: need argmin index -> u64 keys + 16-lane butterfly
#pragma unroll
    for (int x = 0; x < 4; ++x) {
      unsigned long long kmin[4] = {~0ull, ~0ull, ~0ull, ~0ull};
#pragma unroll
      for (int y = 0; y < 4; ++y) {
        const int col = colBase + wc * 64 + y * 16 + lc;
#pragma unroll
        for (int r = 0; r < 4; ++r) {
          const float v = fmaf(-2.f, acc[x][y][r], sb[y]);
          const unsigned long long kn =
              ((unsigned long long)f2o(v) << 32) | (unsigned)col;
          if (kn < kmin[r]) kmin[r] = kn;
        }
      }
#pragma unroll
      for (int r = 0; r < 4; ++r) {
#pragma unroll
        for (int s = 1; s < 16; s <<= 1) {
          const unsigned long long o = __shfl_xor(kmin[r], s, 64);
          if (o < kmin[r]) kmin[r] = o;
        }
      }
      if (lc == 0) {
#pragma unroll
        for (int r = 0; r < 4; ++r)
          rowkey[wr * 64 + x * 16 + quad * 4 + r][wc] = kmin[r];
      }
    }
  }

  __syncthreads();
  if (isProto) {
    if (t < TILE) {
      unsigned long long a = rowkey[t][0];
      const unsigned long long c = rowkey[t][1];
      if (c < a) a = c;
      atomicMin(pr_key + rowBase + t, a);
    }
  } else {
    if (t < TILE) {
      atomicMin(an_u32 + rowBase + t, rmin[t]);
    } else if (t < 2 * TILE) {
      const int i = t - TILE;
      if (colSide) atomicMin(an_u32 + colBase + i, cmin[i]);
      else if (isDiag) atomicMax(ap_u32 + rowBase + i, amax[i]);
    }
  }

  // ---- last-block finalize (replaces the separate finalize_kernel) ----
  // No __threadfence: global atomics are device-scope coherent once retired.
  // Each wave drains its own outstanding atomics (vmcnt), barrier, then one
  // counter bump per block. The block observing NBLK-1 knows all other
  // blocks' atomics have completed.
  asm volatile("s_waitcnt vmcnt(0)" ::: "memory");
  __syncthreads();
  if (t == 0) lastflag = atomicAdd(cnt, 1u);
  __syncthreads();
  if (lastflag == NBLK - 1) {
    float loss = 0.f, sp = 0.f, sn = 0.f, accv = 0.f;
#pragma unroll 8
    for (int i = t; i < NTOT; i += 256) {
      const float s = sq[i];
      const unsigned apu = __hip_atomic_load(&ap_u32[i], __ATOMIC_RELAXED,
                                             __HIP_MEMORY_SCOPE_AGENT);
      const unsigned anu = __hip_atomic_load(&an_u32[i], __ATOMIC_RELAXED,
                                             __HIP_MEMORY_SCOPE_AGENT);
      const unsigned long long pk = __hip_atomic_load(
          &pr_key[i], __ATOMIC_RELAXED, __HIP_MEMORY_SCOPE_AGENT);
      const float apv = sqrtf(fmaxf(s + o2f(apu), 1e-12f));
      const float anv = sqrtf(fmaxf(s + o2f(anu), 1e-12f));
      loss += fmaxf(apv - anv + MARGINV, 0.f);
      sp += apv;
      sn += anv;
      accv += ((unsigned)(pk & 0xffffffffu) == (unsigned)(i >> 3)) ? 1.f : 0.f;
    }
    loss = wave_sum64(loss);
    sp = wave_sum64(sp);
    sn = wave_sum64(sn);
    accv = wave_sum64(accv);
    if (lane == 0) {
      fin_red[wv][0] = loss;
      fin_red[wv][1] = accv;
      fin_red[wv][2] = sp;
      fin_red[wv][3] = sn;
    }
    __syncthreads();
    if (t == 0) {
      float L = 0, Ac = 0, Pm = 0, Nn = 0;
#pragma unroll
      for (int i = 0; i < 4; ++i) {
        L += fin_red[i][0];
        Ac += fin_red[i][1];
        Pm += fin_red[i][2];
        Nn += fin_red[i][3];
      }
      out[0] = L / NTOT;   // W = 1.0
      out[1] = Ac / NTOT;
      out[2] = Pm / NTOT;
      out[3] = Nn / NTOT;
    }
  }
}

extern "C" void kernel_launch(void* const* d_in, const int* in_sizes, int n_in,
                              void* d_out, int out_size, void* d_ws, size_t ws_size,
                              hipStream_t stream) {
  const float* inputs = (const float*)d_in[0];
  float* out = (float*)d_out;
  char* w = (char*)d_ws;
  float* sq  = (float*)(w);                                       // 32 KB
  float* psq = (float*)(w + 32768);                               // 4 KB
  unsigned* an_u32 = (unsigned*)(w + 36864);                      // 32 KB
  unsigned* ap_u32 = (unsigned*)(w + 69632);                      // 32 KB
  unsigned long long* pr_key = (unsigned long long*)(w + 102400); // 64 KB
  unsigned char* A8 = (unsigned char*)(w + 167936);               // 4 MB
  unsigned char* P8 = (unsigned char*)(w + 167936 + (size_t)NTOT * DIM);
  unsigned* cnt = (unsigned*)(w + 167936 + (size_t)NTOT * DIM
                              + (size_t)NWAYS * DIM);             // +4 B

  prep<<<NTOT / 4 + NWAYS / 4, 256, 0, stream>>>(inputs, sq, psq, A8, P8,
                                                 an_u32, ap_u32, pr_key, cnt);
  gemm_fused<<<NBLK, 256, 0, stream>>>(A8, P8, sq, psq,
                                       an_u32, ap_u32, pr_key, out, cnt);
}